// Round 1
// baseline (169.778 us; speedup 1.0000x reference)
//
#include <hip/hip_runtime.h>

#define BINS 4096          // 64 * 64
#define HIST_BLOCKS 1024
#define HIST_THREADS 256

// out[i] = transitions_in[i] for i < bins; out[bins] = total_in + n_events
__global__ void topo_init_kernel(const float* __restrict__ transitions,
                                 const float* __restrict__ total,
                                 float* __restrict__ out,
                                 float n_events_f, int bins) {
    int i = blockIdx.x * blockDim.x + threadIdx.x;
    if (i < bins) out[i] = transitions[i];
    if (i == 0) out[bins] = total[0] + n_events_f;
}

__global__ void __launch_bounds__(HIST_THREADS)
topo_hist_kernel(const int* __restrict__ prev,
                 const int* __restrict__ curr,
                 float* __restrict__ out, int n) {
    __shared__ unsigned int h[BINS];
    for (int i = threadIdx.x; i < BINS; i += HIST_THREADS) h[i] = 0u;
    __syncthreads();

    const int tid = blockIdx.x * HIST_THREADS + threadIdx.x;
    const int stride = gridDim.x * HIST_THREADS;
    const int n4 = n >> 2;

    const int4* __restrict__ p4 = (const int4*)prev;
    const int4* __restrict__ c4 = (const int4*)curr;

    for (int i = tid; i < n4; i += stride) {
        int4 p = p4[i];
        int4 c = c4[i];
        atomicAdd(&h[(p.x << 6) | c.x], 1u);
        atomicAdd(&h[(p.y << 6) | c.y], 1u);
        atomicAdd(&h[(p.z << 6) | c.z], 1u);
        atomicAdd(&h[(p.w << 6) | c.w], 1u);
    }
    // tail (n not divisible by 4 — not hit for 16.7M but kept for safety)
    for (int i = (n4 << 2) + tid; i < n; i += stride) {
        atomicAdd(&h[(prev[i] << 6) | curr[i]], 1u);
    }

    __syncthreads();
    for (int i = threadIdx.x; i < BINS; i += HIST_THREADS) {
        unsigned int c = h[i];
        if (c) atomicAdd(&out[i], (float)c);
    }
}

extern "C" void kernel_launch(void* const* d_in, const int* in_sizes, int n_in,
                              void* d_out, int out_size, void* d_ws, size_t ws_size,
                              hipStream_t stream) {
    const int*   prev        = (const int*)d_in[0];
    const int*   curr        = (const int*)d_in[1];
    const float* transitions = (const float*)d_in[2];
    const float* total       = (const float*)d_in[3];
    float* out = (float*)d_out;

    const int n    = in_sizes[0];
    const int bins = in_sizes[2];   // 4096

    // 1) initialize output: copy transitions input, set total = total_in + n
    int init_blocks = (bins + 1 + 255) / 256;
    topo_init_kernel<<<init_blocks, 256, 0, stream>>>(transitions, total, out,
                                                      (float)n, bins);

    // 2) per-block LDS histogram + global float atomic flush
    topo_hist_kernel<<<HIST_BLOCKS, HIST_THREADS, 0, stream>>>(prev, curr, out, n);
}

// Round 2
// 156.471 us; speedup vs baseline: 1.0850x; 1.0850x over previous
//
#include <hip/hip_runtime.h>

#define BINS 4096          // 64 * 64
#define HIST_BLOCKS 1024
#define HIST_THREADS 512   // 8 waves/block * 4 blocks/CU = 32 waves/CU (100% occ)

// out[i] = transitions_in[i] for i < bins; out[bins] = total_in + n_events
__global__ void topo_init_kernel(const float* __restrict__ transitions,
                                 const float* __restrict__ total,
                                 float* __restrict__ out,
                                 float n_events_f, int bins) {
    int i = blockIdx.x * blockDim.x + threadIdx.x;
    if (i < bins) out[i] = transitions[i];
    if (i == 0) out[bins] = total[0] + n_events_f;
}

__global__ void __launch_bounds__(HIST_THREADS)
topo_hist_kernel(const int* __restrict__ prev,
                 const int* __restrict__ curr,
                 float* __restrict__ out, int n) {
    __shared__ unsigned int h[BINS];
    for (int i = threadIdx.x; i < BINS; i += HIST_THREADS) h[i] = 0u;
    __syncthreads();

    const int n4 = n >> 2;
    const int4* __restrict__ p4 = (const int4*)prev;
    const int4* __restrict__ c4 = (const int4*)curr;

    // Grid-stride with 2x unroll: each thread issues 4 dwordx4 loads (4 KB/wave
    // in flight) before the LDS atomic burst, to hide HBM latency.
    const int base   = blockIdx.x * (HIST_THREADS * 2) + threadIdx.x;
    const int stride = gridDim.x * (HIST_THREADS * 2);

    for (int i = base; i < n4; i += stride) {
        const int j = i + HIST_THREADS;
        int4 p0 = p4[i];
        int4 c0 = c4[i];
        int4 p1, c1;
        const bool ok = (j < n4);
        if (ok) { p1 = p4[j]; c1 = c4[j]; }

        atomicAdd(&h[(p0.x << 6) | c0.x], 1u);
        atomicAdd(&h[(p0.y << 6) | c0.y], 1u);
        atomicAdd(&h[(p0.z << 6) | c0.z], 1u);
        atomicAdd(&h[(p0.w << 6) | c0.w], 1u);
        if (ok) {
            atomicAdd(&h[(p1.x << 6) | c1.x], 1u);
            atomicAdd(&h[(p1.y << 6) | c1.y], 1u);
            atomicAdd(&h[(p1.z << 6) | c1.z], 1u);
            atomicAdd(&h[(p1.w << 6) | c1.w], 1u);
        }
    }
    // tail (n not divisible by 4 — not hit for 16.7M but kept for safety)
    for (int i = (n4 << 2) + blockIdx.x * HIST_THREADS + threadIdx.x; i < n;
         i += gridDim.x * HIST_THREADS) {
        atomicAdd(&h[(prev[i] << 6) | curr[i]], 1u);
    }

    __syncthreads();
    for (int i = threadIdx.x; i < BINS; i += HIST_THREADS) {
        unsigned int c = h[i];
        if (c) atomicAdd(&out[i], (float)c);
    }
}

extern "C" void kernel_launch(void* const* d_in, const int* in_sizes, int n_in,
                              void* d_out, int out_size, void* d_ws, size_t ws_size,
                              hipStream_t stream) {
    const int*   prev        = (const int*)d_in[0];
    const int*   curr        = (const int*)d_in[1];
    const float* transitions = (const float*)d_in[2];
    const float* total       = (const float*)d_in[3];
    float* out = (float*)d_out;

    const int n    = in_sizes[0];
    const int bins = in_sizes[2];   // 4096

    // 1) initialize output: copy transitions input, set total = total_in + n
    int init_blocks = (bins + 1 + 255) / 256;
    topo_init_kernel<<<init_blocks, 256, 0, stream>>>(transitions, total, out,
                                                      (float)n, bins);

    // 2) per-block LDS histogram + global float atomic flush
    topo_hist_kernel<<<HIST_BLOCKS, HIST_THREADS, 0, stream>>>(prev, curr, out, n);
}